// Round 4
// baseline (1087.631 us; speedup 1.0000x reference)
//
#include <hip/hip_runtime.h>
#include <hip/hip_bf16.h>
#include <math.h>

#define N_NODES 5000
#define N_ELEMS 10
#define C_DIM   128
#define N_EDGE  100000
#define N_BES   8
#define RAD_H   64
#define NL      4
#define SH_DIM  16

// scales
#define SC_SCALE 0.02795084971874737f    // 1/sqrt(128*10)
#define X_SCALE  0.08838834764831845f    // 1/sqrt(128)
#define R1_SCALE 0.3535533905932738f     // 1/sqrt(8)
#define R_SCALE  0.125f                  // 1/sqrt(64)
#define OUT_SCALE 0.004419417382415922f  // (1/sqrt(128))/20

__device__ __forceinline__ float silu(float v) { return v / (1.f + __expf(-v)); }

// ---------------- node kernel: sc + x ----------------
__global__ __launch_bounds__(128) void node_kernel(
    const float* __restrict__ node_attrs, const float* __restrict__ node_feats,
    const float* __restrict__ w_skip, const float* __restrict__ w_up,
    float* __restrict__ x, float* __restrict__ sc_out)
{
    int n = blockIdx.x, t = threadIdx.x;
    __shared__ float f[C_DIM];
    __shared__ float at[N_ELEMS];
    f[t] = node_feats[(size_t)n * C_DIM + t];
    if (t < N_ELEMS) at[t] = node_attrs[(size_t)n * N_ELEMS + t];
    __syncthreads();

    // sc[n,d] = sum_a attrs[a] * sum_c f[c] * w_skip[c,a,d]   (attrs one-hot -> 1 pass)
    float acc = 0.f;
    for (int a = 0; a < N_ELEMS; ++a) {
        float av = at[a];
        if (av != 0.f) {                       // uniform branch per block
            const float* wp = w_skip + a * C_DIM + t;
            float s2 = 0.f;
            #pragma unroll 8
            for (int c = 0; c < C_DIM; ++c) s2 += f[c] * wp[(size_t)c * (N_ELEMS * C_DIM)];
            acc += av * s2;
        }
    }
    sc_out[(size_t)n * C_DIM + t] = acc * SC_SCALE;

    // x[n,c] = sum_k f[k] * w_up[k,c] / sqrt(C)
    float xa = 0.f;
    #pragma unroll 8
    for (int k = 0; k < C_DIM; ++k) xa += f[k] * w_up[k * C_DIM + t];
    x[(size_t)n * C_DIM + t] = xa * X_SCALE;
}

// ---------------- radial MLP layers 1-3 -> h3 ----------------
__global__ __launch_bounds__(256) void radial_kernel(
    const float* __restrict__ edge_feats,
    const float* __restrict__ w1, const float* __restrict__ w2, const float* __restrict__ w3,
    float* __restrict__ h3out)
{
    __shared__ float w1s[N_BES * RAD_H];
    __shared__ float w2s[RAD_H * RAD_H];
    __shared__ float w3s[RAD_H * RAD_H];
    __shared__ float h1s[4][RAD_H];
    __shared__ float h2s[4][RAD_H];
    int t = threadIdx.x;
    for (int i = t; i < N_BES * RAD_H; i += 256) w1s[i] = w1[i];
    for (int i = t; i < RAD_H * RAD_H; i += 256) { w2s[i] = w2[i]; w3s[i] = w3[i]; }
    __syncthreads();
    int sub = t >> 6, j = t & 63;
    for (int e0 = blockIdx.x * 4; e0 < N_EDGE; e0 += gridDim.x * 4) {
        int e = e0 + sub;
        if (e < N_EDGE) {
            float a = 0.f;
            #pragma unroll
            for (int k = 0; k < N_BES; ++k) a += edge_feats[(size_t)e * N_BES + k] * w1s[k * RAD_H + j];
            h1s[sub][j] = silu(a * R1_SCALE);
        }
        __syncthreads();
        if (e < N_EDGE) {
            float a = 0.f;
            #pragma unroll 8
            for (int k = 0; k < RAD_H; ++k) a += h1s[sub][k] * w2s[k * RAD_H + j];
            h2s[sub][j] = silu(a * R_SCALE);
        }
        __syncthreads();
        if (e < N_EDGE) {
            float a = 0.f;
            #pragma unroll 8
            for (int k = 0; k < RAD_H; ++k) a += h2s[sub][k] * w3s[k * RAD_H + j];
            h3out[(size_t)e * RAD_H + j] = silu(a * R_SCALE);
        }
        __syncthreads();
    }
}

// ---------------- tp_w = h3 @ w_rad4 (per-l slice in LDS) ----------------
__global__ __launch_bounds__(256) void tpw_kernel(
    const float* __restrict__ h3, const float* __restrict__ w4, float* __restrict__ tpw)
{
    int l = blockIdx.y, t = threadIdx.x;
    __shared__ float w4s[RAD_H * C_DIM];   // 32 KB
    __shared__ float hs[2][RAD_H];
    for (int i = t; i < RAD_H * C_DIM; i += 256) {
        int r = i >> 7, c = i & 127;
        w4s[i] = w4[r * (NL * C_DIM) + l * C_DIM + c];
    }
    int p = t >> 7, c = t & 127;
    for (int eb = blockIdx.x * 2; eb < N_EDGE; eb += gridDim.x * 2) {
        __syncthreads();   // protects hs readers of prev iter (and w4s staging on iter 0)
        if (t < 128) { int ee = eb + (t >> 6); if (ee < N_EDGE) hs[t >> 6][t & 63] = h3[(size_t)ee * RAD_H + (t & 63)]; }
        __syncthreads();
        int e = eb + p;
        if (e < N_EDGE) {
            float a = 0.f;
            #pragma unroll 8
            for (int k = 0; k < RAD_H; ++k) a += hs[p][k] * w4s[k * C_DIM + c];
            tpw[(size_t)e * (NL * C_DIM) + l * C_DIM + c] = a * R_SCALE;
        }
    }
}

// ---------------- CSR build ----------------
__global__ void hist_kernel(const int* __restrict__ recv, int* __restrict__ deg)
{
    int e = blockIdx.x * 256 + threadIdx.x;
    if (e < N_EDGE) atomicAdd(&deg[recv[e]], 1);
}

__global__ __launch_bounds__(256) void scan_kernel(const int* __restrict__ deg, int* __restrict__ offs)
{
    __shared__ int sums[256];
    int t = threadIdx.x;
    int base = t * 20;
    int loc[20]; int s = 0;
    #pragma unroll
    for (int i = 0; i < 20; ++i) { int idx = base + i; int v = (idx < N_NODES) ? deg[idx] : 0; loc[i] = s; s += v; }
    sums[t] = s; __syncthreads();
    for (int off = 1; off < 256; off <<= 1) {
        int v = (t >= off) ? sums[t - off] : 0;
        __syncthreads();
        sums[t] += v;
        __syncthreads();
    }
    int ex = (t == 0) ? 0 : sums[t - 1];
    #pragma unroll
    for (int i = 0; i < 20; ++i) { int idx = base + i; if (idx < N_NODES) offs[idx] = ex + loc[i]; }
    if (t == 255) offs[N_NODES] = sums[255];
}

__global__ void scatter_kernel(const int* __restrict__ recv, const int* __restrict__ offs,
                               int* __restrict__ cursor, int* __restrict__ perm)
{
    int e = blockIdx.x * 256 + threadIdx.x;
    if (e < N_EDGE) {
        int r = recv[e];
        int pos = atomicAdd(&cursor[r], 1);
        perm[offs[r] + pos] = e;
    }
}

// ---------------- gather: msg[n,m,c] = sum_{e->n} ea[e,m]*x[s,c]*tpw[e,l(m),c] ----------------
__global__ __launch_bounds__(256) void gather_kernel(
    const int* __restrict__ perm, const int* __restrict__ offs,
    const int* __restrict__ sender, const float* __restrict__ x,
    const float* __restrict__ edge_attrs, const float* __restrict__ tpw,
    float* __restrict__ msg)
{
    int n = blockIdx.x, t = threadIdx.x;
    int c = t & 127, g = t >> 7;
    __shared__ float xs[C_DIM];
    __shared__ float eas[SH_DIM];
    __shared__ float tps[NL * C_DIM];
    float acc[8] = {0.f, 0.f, 0.f, 0.f, 0.f, 0.f, 0.f, 0.f};
    int start = offs[n], end = offs[n + 1];
    for (int idx = start; idx < end; ++idx) {
        int e = perm[idx];
        __syncthreads();
        if (t < C_DIM) xs[t] = x[(size_t)sender[e] * C_DIM + t];
        if (t >= 128 && t < 128 + SH_DIM) eas[t - 128] = edge_attrs[(size_t)e * SH_DIM + (t - 128)];
        tps[t] = tpw[(size_t)e * (NL * C_DIM) + t];
        tps[256 + t] = tpw[(size_t)e * (NL * C_DIM) + 256 + t];
        __syncthreads();
        float xv = xs[c];
        #pragma unroll
        for (int j = 0; j < 8; ++j) {
            int m = g * 8 + j;
            int l = (m >= 9) ? 3 : ((m >= 4) ? 2 : ((m >= 1) ? 1 : 0));
            acc[j] += eas[m] * xv * tps[l * C_DIM + c];
        }
    }
    #pragma unroll
    for (int j = 0; j < 8; ++j)
        msg[(size_t)n * (SH_DIM * C_DIM) + (g * 8 + j) * C_DIM + c] = acc[j];
}

// ---------------- fallback: atomic scatter (small workspace) ----------------
__global__ __launch_bounds__(256) void msg_atomic_kernel(
    const float* __restrict__ h3, const float* __restrict__ w4,
    const float* __restrict__ x, const float* __restrict__ edge_attrs,
    const int* __restrict__ sender, const int* __restrict__ recv,
    float* __restrict__ msg)
{
    int l = blockIdx.y, t = threadIdx.x;
    __shared__ float w4s[RAD_H * C_DIM];
    __shared__ float hs[2][RAD_H];
    for (int i = t; i < RAD_H * C_DIM; i += 256) {
        int r = i >> 7, c = i & 127;
        w4s[i] = w4[r * (NL * C_DIM) + l * C_DIM + c];
    }
    int p = t >> 7, c = t & 127;
    int ms = l * l, cnt = 2 * l + 1;
    for (int eb = blockIdx.x * 2; eb < N_EDGE; eb += gridDim.x * 2) {
        __syncthreads();
        if (t < 128) { int ee = eb + (t >> 6); if (ee < N_EDGE) hs[t >> 6][t & 63] = h3[(size_t)ee * RAD_H + (t & 63)]; }
        __syncthreads();
        int e = eb + p;
        if (e < N_EDGE) {
            float a = 0.f;
            #pragma unroll 8
            for (int k = 0; k < RAD_H; ++k) a += hs[p][k] * w4s[k * C_DIM + c];
            float tp = a * R_SCALE;
            float xv = x[(size_t)sender[e] * C_DIM + c];
            float* mbase = msg + (size_t)recv[e] * (SH_DIM * C_DIM) + c;
            for (int mi = 0; mi < cnt; ++mi) {
                int m = ms + mi;
                atomicAdd(mbase + m * C_DIM, edge_attrs[(size_t)e * SH_DIM + m] * xv * tp);
            }
        }
    }
}

// ---------------- out[n,m,d] = sum_c msg[n,m,c]*w_out[l(m),c,d] ----------------
__global__ __launch_bounds__(256) void out_kernel(
    const float* __restrict__ msg, const float* __restrict__ w_out, float* __restrict__ out)
{
    int nb = blockIdx.x * 4, t = threadIdx.x;
    int d = t & 127, p = t >> 7;
    __shared__ float msgs[4 * SH_DIM * C_DIM];   // 32 KB
    for (int i = t; i < 4 * SH_DIM * C_DIM; i += 256) msgs[i] = msg[(size_t)nb * (SH_DIM * C_DIM) + i];
    __syncthreads();
    for (int l = 0; l < 4; ++l) {
        int ms = l * l, cnt = 2 * l + 1;
        int rows = 4 * cnt;
        const float* wbase = w_out + (size_t)l * C_DIM * C_DIM + d;
        for (int rr = p; rr < rows; rr += 2) {
            int node = rr / cnt, mm = ms + rr % cnt;
            const float* mp = msgs + node * (SH_DIM * C_DIM) + mm * C_DIM;
            float a = 0.f;
            #pragma unroll 8
            for (int cc = 0; cc < C_DIM; ++cc) a += mp[cc] * wbase[(size_t)cc * C_DIM];
            out[(size_t)(nb + node) * (SH_DIM * C_DIM) + mm * C_DIM + d] = a * OUT_SCALE;
        }
    }
}

extern "C" void kernel_launch(void* const* d_in, const int* in_sizes, int n_in,
                              void* d_out, int out_size, void* d_ws, size_t ws_size,
                              hipStream_t stream)
{
    const float* node_attrs = (const float*)d_in[0];
    const float* node_feats = (const float*)d_in[1];
    const float* edge_attrs = (const float*)d_in[2];
    const float* edge_feats = (const float*)d_in[3];
    const int*   edge_index = (const int*)d_in[4];
    const float* w_up   = (const float*)d_in[5];
    const float* w_rad1 = (const float*)d_in[6];
    const float* w_rad2 = (const float*)d_in[7];
    const float* w_rad3 = (const float*)d_in[8];
    const float* w_rad4 = (const float*)d_in[9];
    const float* w_skip = (const float*)d_in[10];
    const float* w_out  = (const float*)d_in[11];
    const int* sender = edge_index;
    const int* recv   = edge_index + N_EDGE;

    float* out = (float*)d_out;                                 // 5000*2048
    float* sc  = out + (size_t)N_NODES * SH_DIM * C_DIM;        // 5000*128

    // workspace layout
    float* x   = (float*)d_ws;                                  // 640,000 f
    float* h3  = x + (size_t)N_NODES * C_DIM;                   // 6,400,000 f
    float* msg = h3 + (size_t)N_EDGE * RAD_H;                   // 10,240,000 f
    int* deg    = (int*)(msg + (size_t)N_NODES * SH_DIM * C_DIM);
    int* cursor = deg + 5120;
    int* offs   = cursor + 5120;                                // 5001 used
    int* perm   = offs + 5124;                                  // 100,000
    float* tpw  = (float*)(perm + N_EDGE);                      // 51,200,000 f (204.8 MB)
    size_t big_need = (size_t)((char*)(tpw + (size_t)N_EDGE * NL * C_DIM) - (char*)d_ws);
    bool big = ws_size >= big_need;

    node_kernel<<<N_NODES, 128, 0, stream>>>(node_attrs, node_feats, w_skip, w_up, x, sc);
    radial_kernel<<<1024, 256, 0, stream>>>(edge_feats, w_rad1, w_rad2, w_rad3, h3);

    if (big) {
        hipMemsetAsync(deg, 0, 2 * 5120 * sizeof(int), stream);           // deg + cursor
        tpw_kernel<<<dim3(512, 4), 256, 0, stream>>>(h3, w_rad4, tpw);
        hist_kernel<<<(N_EDGE + 255) / 256, 256, 0, stream>>>(recv, deg);
        scan_kernel<<<1, 256, 0, stream>>>(deg, offs);
        scatter_kernel<<<(N_EDGE + 255) / 256, 256, 0, stream>>>(recv, offs, cursor, perm);
        gather_kernel<<<N_NODES, 256, 0, stream>>>(perm, offs, sender, x, edge_attrs, tpw, msg);
    } else {
        hipMemsetAsync(msg, 0, (size_t)N_NODES * SH_DIM * C_DIM * sizeof(float), stream);
        msg_atomic_kernel<<<dim3(512, 4), 256, 0, stream>>>(h3, w_rad4, x, edge_attrs, sender, recv, msg);
    }

    out_kernel<<<N_NODES / 4, 256, 0, stream>>>(msg, w_out, out);
}

// Round 5
// 548.869 us; speedup vs baseline: 1.9816x; 1.9816x over previous
//
#include <hip/hip_runtime.h>
#include <hip/hip_bf16.h>
#include <math.h>

#define N_NODES 5000
#define N_ELEMS 10
#define C_DIM   128
#define N_EDGE  100000
#define N_BES   8
#define RAD_H   64
#define NL      4
#define SH_DIM  16

// scales
#define SC_SCALE 0.02795084971874737f    // 1/sqrt(128*10)
#define X_SCALE  0.08838834764831845f    // 1/sqrt(128)
#define R1_SCALE 0.3535533905932738f     // 1/sqrt(8)
#define R_SCALE  0.125f                  // 1/sqrt(64)
#define OUT_SCALE 0.004419417382415922f  // (1/sqrt(128))/20

__device__ __forceinline__ float silu(float v) { return v / (1.f + __expf(-v)); }

// ---------------- node kernel: sc + x ----------------
__global__ __launch_bounds__(128) void node_kernel(
    const float* __restrict__ node_attrs, const float* __restrict__ node_feats,
    const float* __restrict__ w_skip, const float* __restrict__ w_up,
    float* __restrict__ x, float* __restrict__ sc_out)
{
    int n = blockIdx.x, t = threadIdx.x;
    __shared__ float f[C_DIM];
    __shared__ float at[N_ELEMS];
    f[t] = node_feats[(size_t)n * C_DIM + t];
    if (t < N_ELEMS) at[t] = node_attrs[(size_t)n * N_ELEMS + t];
    __syncthreads();

    // sc[n,d] = sum_a attrs[a] * sum_c f[c] * w_skip[c,a,d]   (attrs one-hot -> 1 pass)
    float acc = 0.f;
    for (int a = 0; a < N_ELEMS; ++a) {
        float av = at[a];
        if (av != 0.f) {                       // uniform branch per block
            const float* wp = w_skip + a * C_DIM + t;
            float s2 = 0.f;
            #pragma unroll 8
            for (int c = 0; c < C_DIM; ++c) s2 += f[c] * wp[(size_t)c * (N_ELEMS * C_DIM)];
            acc += av * s2;
        }
    }
    sc_out[(size_t)n * C_DIM + t] = acc * SC_SCALE;

    // x[n,c] = sum_k f[k] * w_up[k,c] / sqrt(C)
    float xa = 0.f;
    #pragma unroll 8
    for (int k = 0; k < C_DIM; ++k) xa += f[k] * w_up[k * C_DIM + t];
    x[(size_t)n * C_DIM + t] = xa * X_SCALE;
}

// ---------------- radial MLP layers 1-3 -> h3 ----------------
__global__ __launch_bounds__(256) void radial_kernel(
    const float* __restrict__ edge_feats,
    const float* __restrict__ w1, const float* __restrict__ w2, const float* __restrict__ w3,
    float* __restrict__ h3out)
{
    __shared__ float w1s[N_BES * RAD_H];
    __shared__ float w2s[RAD_H * RAD_H];
    __shared__ float w3s[RAD_H * RAD_H];
    __shared__ float h1s[4][RAD_H];
    __shared__ float h2s[4][RAD_H];
    int t = threadIdx.x;
    for (int i = t; i < N_BES * RAD_H; i += 256) w1s[i] = w1[i];
    for (int i = t; i < RAD_H * RAD_H; i += 256) { w2s[i] = w2[i]; w3s[i] = w3[i]; }
    __syncthreads();
    int sub = t >> 6, j = t & 63;
    for (int e0 = blockIdx.x * 4; e0 < N_EDGE; e0 += gridDim.x * 4) {
        int e = e0 + sub;
        if (e < N_EDGE) {
            float a = 0.f;
            #pragma unroll
            for (int k = 0; k < N_BES; ++k) a += edge_feats[(size_t)e * N_BES + k] * w1s[k * RAD_H + j];
            h1s[sub][j] = silu(a * R1_SCALE);
        }
        __syncthreads();
        if (e < N_EDGE) {
            float a = 0.f;
            #pragma unroll 8
            for (int k = 0; k < RAD_H; ++k) a += h1s[sub][k] * w2s[k * RAD_H + j];
            h2s[sub][j] = silu(a * R_SCALE);
        }
        __syncthreads();
        if (e < N_EDGE) {
            float a = 0.f;
            #pragma unroll 8
            for (int k = 0; k < RAD_H; ++k) a += h2s[sub][k] * w3s[k * RAD_H + j];
            h3out[(size_t)e * RAD_H + j] = silu(a * R_SCALE);
        }
        __syncthreads();
    }
}

// ---------------- CSR build ----------------
__global__ void hist_kernel(const int* __restrict__ recv, int* __restrict__ deg)
{
    int e = blockIdx.x * 256 + threadIdx.x;
    if (e < N_EDGE) atomicAdd(&deg[recv[e]], 1);
}

__global__ __launch_bounds__(256) void scan_kernel(const int* __restrict__ deg, int* __restrict__ offs)
{
    __shared__ int sums[256];
    int t = threadIdx.x;
    int base = t * 20;
    int loc[20]; int s = 0;
    #pragma unroll
    for (int i = 0; i < 20; ++i) { int idx = base + i; int v = (idx < N_NODES) ? deg[idx] : 0; loc[i] = s; s += v; }
    sums[t] = s; __syncthreads();
    for (int off = 1; off < 256; off <<= 1) {
        int v = (t >= off) ? sums[t - off] : 0;
        __syncthreads();
        sums[t] += v;
        __syncthreads();
    }
    int ex = (t == 0) ? 0 : sums[t - 1];
    #pragma unroll
    for (int i = 0; i < 20; ++i) { int idx = base + i; if (idx < N_NODES) offs[idx] = ex + loc[i]; }
    if (t == 255) offs[N_NODES] = sums[255];
}

__global__ void scatter_kernel(const int* __restrict__ recv, const int* __restrict__ offs,
                               int* __restrict__ cursor, int* __restrict__ perm)
{
    int e = blockIdx.x * 256 + threadIdx.x;
    if (e < N_EDGE) {
        int r = recv[e];
        int pos = atomicAdd(&cursor[r], 1);
        perm[offs[r] + pos] = e;
    }
}

// ---------------- fused gather: tp_w recompute + message accumulate ----------------
// One block per node, 512 threads: thread (l = t>>7, c = t&127).
// Each thread holds w_rad4 column [64] in registers, computes tp[l,c] per edge
// (h3 row read via scalar loads - edge idx forced uniform), accumulates 2l+1 m-slots.
// msg written to d_out (out region), transformed in place by out_kernel after.
__global__ __launch_bounds__(512, 4) void fused_gather_kernel(
    const int* __restrict__ perm, const int* __restrict__ offs,
    const int* __restrict__ sender, const float* __restrict__ x,
    const float* __restrict__ edge_attrs, const float* __restrict__ h3,
    const float* __restrict__ w4, float* __restrict__ msg)
{
    int n = blockIdx.x, t = threadIdx.x;
    int c = t & 127, l = t >> 7;          // l in 0..3
    // stage this thread's w_rad4 column into registers (coalesced per k)
    float wc[RAD_H];
    #pragma unroll
    for (int k = 0; k < RAD_H; ++k)
        wc[k] = w4[k * (NL * C_DIM) + l * C_DIM + c];

    float acc[7] = {0.f, 0.f, 0.f, 0.f, 0.f, 0.f, 0.f};
    int nm = 2 * l + 1;
    int start = offs[n], end = offs[n + 1];
    for (int idx = start; idx < end; ++idx) {
        int e = __builtin_amdgcn_readfirstlane(perm[idx]);
        int s = __builtin_amdgcn_readfirstlane(sender[e]);
        float xv = x[(size_t)s * C_DIM + c];
        const float* h3r = h3 + (size_t)e * RAD_H;     // uniform address -> scalar loads
        float tp = 0.f;
        #pragma unroll
        for (int k = 0; k < RAD_H; ++k) tp += h3r[k] * wc[k];
        float xt = xv * (tp * R_SCALE);
        const float* ear = edge_attrs + (size_t)e * SH_DIM + l * l;
        #pragma unroll
        for (int j = 0; j < 7; ++j)
            if (j < nm) acc[j] += ear[j] * xt;
    }
    float* mout = msg + (size_t)n * (SH_DIM * C_DIM) + (size_t)(l * l) * C_DIM + c;
    #pragma unroll
    for (int j = 0; j < 7; ++j)
        if (j < nm) mout[(size_t)j * C_DIM] = acc[j];
}

// ---------------- out[n,m,d] = sum_c msg[n,m,c]*w_out[l(m),c,d]  (in place on d_out) ----------------
__global__ __launch_bounds__(256) void out_kernel(
    float* __restrict__ out, const float* __restrict__ w_out)
{
    int nb = blockIdx.x * 4, t = threadIdx.x;
    int d = t & 127, p = t >> 7;
    __shared__ float msgs[4 * SH_DIM * C_DIM];   // 32 KB
    for (int i = t; i < 4 * SH_DIM * C_DIM; i += 256) msgs[i] = out[(size_t)nb * (SH_DIM * C_DIM) + i];
    __syncthreads();
    for (int l = 0; l < 4; ++l) {
        int ms = l * l, cnt = 2 * l + 1;
        int rows = 4 * cnt;
        const float* wbase = w_out + (size_t)l * C_DIM * C_DIM + d;
        for (int rr = p; rr < rows; rr += 2) {
            int node = rr / cnt, mm = ms + rr % cnt;
            const float* mp = msgs + node * (SH_DIM * C_DIM) + mm * C_DIM;
            float a = 0.f;
            #pragma unroll 8
            for (int cc = 0; cc < C_DIM; ++cc) a += mp[cc] * wbase[(size_t)cc * C_DIM];
            out[(size_t)(nb + node) * (SH_DIM * C_DIM) + mm * C_DIM + d] = a * OUT_SCALE;
        }
    }
}

extern "C" void kernel_launch(void* const* d_in, const int* in_sizes, int n_in,
                              void* d_out, int out_size, void* d_ws, size_t ws_size,
                              hipStream_t stream)
{
    const float* node_attrs = (const float*)d_in[0];
    const float* node_feats = (const float*)d_in[1];
    const float* edge_attrs = (const float*)d_in[2];
    const float* edge_feats = (const float*)d_in[3];
    const int*   edge_index = (const int*)d_in[4];
    const float* w_up   = (const float*)d_in[5];
    const float* w_rad1 = (const float*)d_in[6];
    const float* w_rad2 = (const float*)d_in[7];
    const float* w_rad3 = (const float*)d_in[8];
    const float* w_rad4 = (const float*)d_in[9];
    const float* w_skip = (const float*)d_in[10];
    const float* w_out  = (const float*)d_in[11];
    const int* sender = edge_index;
    const int* recv   = edge_index + N_EDGE;

    float* out = (float*)d_out;                                 // 5000*2048 (msg staged here first)
    float* sc  = out + (size_t)N_NODES * SH_DIM * C_DIM;        // 5000*128

    // workspace layout (28.6 MB; known ws_size >= 69 MB from round-4 evidence)
    float* x   = (float*)d_ws;                                  // 640,000 f
    float* h3  = x + (size_t)N_NODES * C_DIM;                   // 6,400,000 f
    int* deg    = (int*)(h3 + (size_t)N_EDGE * RAD_H);          // 5120
    int* cursor = deg + 5120;                                   // 5120
    int* offs   = cursor + 5120;                                // 5001 used (pad 5124)
    int* perm   = offs + 5124;                                  // 100,000

    hipMemsetAsync(deg, 0, 2 * 5120 * sizeof(int), stream);     // deg + cursor

    node_kernel<<<N_NODES, 128, 0, stream>>>(node_attrs, node_feats, w_skip, w_up, x, sc);
    radial_kernel<<<1024, 256, 0, stream>>>(edge_feats, w_rad1, w_rad2, w_rad3, h3);

    hist_kernel<<<(N_EDGE + 255) / 256, 256, 0, stream>>>(recv, deg);
    scan_kernel<<<1, 256, 0, stream>>>(deg, offs);
    scatter_kernel<<<(N_EDGE + 255) / 256, 256, 0, stream>>>(recv, offs, cursor, perm);

    fused_gather_kernel<<<N_NODES, 512, 0, stream>>>(perm, offs, sender, x, edge_attrs, h3, w_rad4, out);
    out_kernel<<<N_NODES / 4, 256, 0, stream>>>(out, w_out);
}